// Round 2
// baseline (544.952 us; speedup 1.0000x reference)
//
#include <hip/hip_runtime.h>

typedef __bf16 bf16_t;
typedef __bf16 bf16x8 __attribute__((ext_vector_type(8)));
typedef __bf16 bf16x4 __attribute__((ext_vector_type(4)));
typedef float f32x4 __attribute__((ext_vector_type(4)));

#define D_MODEL 1024
#define NHEAD 16
#define HD 64
#define XLEN 1024
#define TLEN 4096
#define NBATCH 2

// ---- dtype probe: decide if inputs are fp32 (flag=1) or bf16 (flag=0). ----
// If Wq is fp32, its even 16-bit halves are float mantissa bits: the bf16
// exponent field of those halves is ~uniform 0..255 -> mostly "wild".
// If Wq is bf16 (~N(0,1/32) values), exponents sit near 110..127 -> ~0 wild.
__global__ void dtype_probe(const unsigned short* __restrict__ w, int* flag) {
    __shared__ int wild;
    if (threadIdx.x == 0) wild = 0;
    __syncthreads();
    int cnt = 0;
    for (int i = threadIdx.x; i < 1024; i += 256) {
        unsigned short u = w[2 * i];
        int e = (u >> 7) & 0xFF;
        if (e >= 140 || (e >= 1 && e <= 90)) cnt++;
    }
    atomicAdd(&wild, cnt);
    __syncthreads();
    if (threadIdx.x == 0) *flag = (wild > 100) ? 1 : 0;
}

// ---- input conversion: fp32 -> bf16 (when flag), bf16 copy (when force). ----
__global__ void convert_in(const void* __restrict__ src, bf16_t* __restrict__ dst,
                           int n, const int* __restrict__ flag, int force) {
    const int isf32 = *flag;
    int i = blockIdx.x * blockDim.x + threadIdx.x;
    const int stride = gridDim.x * blockDim.x;
    if (isf32) {
        const float* s = (const float*)src;
        for (; i < n; i += stride) dst[i] = (bf16_t)s[i];
    } else if (force) {
        const bf16_t* s = (const bf16_t*)src;
        for (; i < n; i += stride) dst[i] = s[i];
    }
}

// Out[m][n] = sum_k X[m][k] * W[n][k] + bias[n]; fp32 accum, bf16 out.
__global__ __launch_bounds__(256) void proj_gemm(const void* __restrict__ Xorig,
                                                 const bf16_t* __restrict__ Xconv,
                                                 const void* __restrict__ Worig,
                                                 const bf16_t* __restrict__ Wconv,
                                                 const bf16_t* __restrict__ bias_c,
                                                 bf16_t* __restrict__ Out,
                                                 int M, const int* __restrict__ flag) {
    const int isf32 = *flag;
    const bf16_t* Xin = isf32 ? Xconv : (const bf16_t*)Xorig;
    const bf16_t* W   = isf32 ? Wconv : (const bf16_t*)Worig;

    const int lane = threadIdx.x & 63;
    const int wid  = (blockIdx.x * blockDim.x + threadIdx.x) >> 6;
    const int nt = wid & 15;
    const int mt = wid >> 4;
    const int m0 = mt * 32;
    const int n0 = nt * 64;
    if (m0 >= M) return;
    const int q = lane >> 4;
    const int c = lane & 15;

    f32x4 acc[2][4];
    for (int i = 0; i < 2; ++i)
        for (int j = 0; j < 4; ++j)
            acc[i][j] = (f32x4){0.f, 0.f, 0.f, 0.f};

    for (int kk = 0; kk < D_MODEL; kk += 32) {
        bf16x8 a[2], b[4];
#pragma unroll
        for (int mi = 0; mi < 2; ++mi)
            a[mi] = *(const bf16x8*)(Xin + (size_t)(m0 + mi * 16 + c) * D_MODEL + kk + q * 8);
#pragma unroll
        for (int ni = 0; ni < 4; ++ni)
            b[ni] = *(const bf16x8*)(W + (size_t)(n0 + ni * 16 + c) * D_MODEL + kk + q * 8);
#pragma unroll
        for (int mi = 0; mi < 2; ++mi)
#pragma unroll
            for (int ni = 0; ni < 4; ++ni)
                acc[mi][ni] = __builtin_amdgcn_mfma_f32_16x16x32_bf16(a[mi], b[ni], acc[mi][ni], 0, 0, 0);
    }

    float bv[4];
#pragma unroll
    for (int ni = 0; ni < 4; ++ni) bv[ni] = (float)bias_c[n0 + ni * 16 + c];

#pragma unroll
    for (int mi = 0; mi < 2; ++mi)
#pragma unroll
        for (int ni = 0; ni < 4; ++ni)
#pragma unroll
            for (int r = 0; r < 4; ++r) {
                int row = m0 + mi * 16 + q * 4 + r;
                int col = n0 + ni * 16 + c;
                Out[(size_t)row * D_MODEL + col] = (bf16_t)(acc[mi][ni][r] + bv[ni]);
            }
}

// Flash attention: block = 4 waves = one (n,h) and 64 q-rows; wave = 16 q-rows.
__global__ __launch_bounds__(256) void attn_kernel(const bf16_t* __restrict__ Q,
                                                   const bf16_t* __restrict__ K,
                                                   const bf16_t* __restrict__ V,
                                                   void* __restrict__ Out,
                                                   const int* __restrict__ flag) {
    __shared__ bf16_t Klds[32][72];
    __shared__ bf16_t Vt[64][44];
    __shared__ bf16_t Plds[4][16][40];

    const int isf32 = *flag;
    const int tid  = threadIdx.x;
    const int lane = tid & 63;
    const int w    = tid >> 6;
    const int q4   = lane >> 4;
    const int c    = lane & 15;

    const int bid  = blockIdx.x;
    const int xblk = bid & 15;
    const int h    = (bid >> 4) & 15;
    const int n    = bid >> 8;

    const int x0 = xblk * 64 + w * 16;

    bf16x8 qa[2];
    {
        const bf16_t* qrow = Q + (size_t)(n * XLEN + x0 + c) * D_MODEL + h * HD + q4 * 8;
        qa[0] = *(const bf16x8*)(qrow);
        qa[1] = *(const bf16x8*)(qrow + 32);
    }

    f32x4 o[4];
    for (int i = 0; i < 4; ++i) o[i] = (f32x4){0.f, 0.f, 0.f, 0.f};
    float mrow[4], lrow[4];
    for (int r = 0; r < 4; ++r) { mrow[r] = -3.0e38f; lrow[r] = 0.0f; }

    const int tstage = tid >> 3;
    const int dstage = (tid & 7) * 8;

    for (int t0 = 0; t0 < TLEN; t0 += 32) {
        __syncthreads();
        {
            const size_t rowbase = (size_t)(n * TLEN + t0 + tstage) * D_MODEL + h * HD + dstage;
            *(bf16x8*)&Klds[tstage][dstage] = *(const bf16x8*)(K + rowbase);
            bf16x8 v8 = *(const bf16x8*)(V + rowbase);
#pragma unroll
            for (int j = 0; j < 8; ++j) Vt[dstage + j][tstage] = v8[j];
        }
        __syncthreads();

        // S = Q K^T / 8
        f32x4 s[2];
#pragma unroll
        for (int tt = 0; tt < 2; ++tt) {
            bf16x8 b0 = *(const bf16x8*)&Klds[tt * 16 + c][q4 * 8];
            bf16x8 b1 = *(const bf16x8*)&Klds[tt * 16 + c][q4 * 8 + 32];
            f32x4 acc = (f32x4){0.f, 0.f, 0.f, 0.f};
            acc = __builtin_amdgcn_mfma_f32_16x16x32_bf16(qa[0], b0, acc, 0, 0, 0);
            acc = __builtin_amdgcn_mfma_f32_16x16x32_bf16(qa[1], b1, acc, 0, 0, 0);
            s[tt] = acc * 0.125f;
        }

        // online softmax over these 32 columns
        float p0[4], p1[4], alpha[4];
#pragma unroll
        for (int r = 0; r < 4; ++r) {
            float mx = fmaxf(s[0][r], s[1][r]);
#pragma unroll
            for (int off = 1; off < 16; off <<= 1) mx = fmaxf(mx, __shfl_xor(mx, off));
            float mnew = fmaxf(mrow[r], mx);
            alpha[r] = __expf(mrow[r] - mnew);
            p0[r] = __expf(s[0][r] - mnew);
            p1[r] = __expf(s[1][r] - mnew);
            float rs = p0[r] + p1[r];
#pragma unroll
            for (int off = 1; off < 16; off <<= 1) rs += __shfl_xor(rs, off);
            lrow[r] = lrow[r] * alpha[r] + rs;
            mrow[r] = mnew;
        }
#pragma unroll
        for (int dc = 0; dc < 4; ++dc) {
            f32x4 t = o[dc];
            t[0] *= alpha[0]; t[1] *= alpha[1]; t[2] *= alpha[2]; t[3] *= alpha[3];
            o[dc] = t;
        }

        // P (C-layout) -> LDS -> A-layout (wave-private region)
#pragma unroll
        for (int r = 0; r < 4; ++r) {
            Plds[w][q4 * 4 + r][c]      = (bf16_t)p0[r];
            Plds[w][q4 * 4 + r][c + 16] = (bf16_t)p1[r];
        }
        bf16x8 pa = *(const bf16x8*)&Plds[w][c][q4 * 8];

        // O += P V
#pragma unroll
        for (int dc = 0; dc < 4; ++dc) {
            bf16x4 bv0 = *(const bf16x4*)&Vt[dc * 16 + c][q4 * 8];
            bf16x4 bv1 = *(const bf16x4*)&Vt[dc * 16 + c][q4 * 8 + 4];
            bf16x8 bb;
#pragma unroll
            for (int j = 0; j < 4; ++j) { bb[j] = bv0[j]; bb[4 + j] = bv1[j]; }
            o[dc] = __builtin_amdgcn_mfma_f32_16x16x32_bf16(pa, bb, o[dc], 0, 0, 0);
        }
    }

#pragma unroll
    for (int dc = 0; dc < 4; ++dc)
#pragma unroll
        for (int r = 0; r < 4; ++r) {
            float val = o[dc][r] / lrow[r];
            int x = x0 + q4 * 4 + r;
            int d = h * HD + dc * 16 + c;
            size_t idx = (size_t)(n * XLEN + x) * D_MODEL + d;
            if (isf32) ((float*)Out)[idx] = val;
            else       ((bf16_t*)Out)[idx] = (bf16_t)val;
        }
}

extern "C" void kernel_launch(void* const* d_in, const int* in_sizes, int n_in,
                              void* d_out, int out_size, void* d_ws, size_t ws_size,
                              hipStream_t stream) {
    (void)in_sizes; (void)n_in; (void)out_size; (void)ws_size;
    const void* prev = d_in[0];
    const void* ctx  = d_in[1];
    const void* Wq   = d_in[2];
    const void* bq   = d_in[3];
    const void* Wk   = d_in[4];
    const void* bk   = d_in[5];
    const void* Wv   = d_in[6];
    const void* bv   = d_in[7];

    const size_t MiB = 1024 * 1024;
    char* ws = (char*)d_ws;
    int*    flag   = (int*)ws;
    bf16_t* Qb     = (bf16_t*)(ws + 1024);                 //  4 MiB (2M el)
    bf16_t* Kb     = (bf16_t*)(ws + 1024 + 4  * MiB);      // 16 MiB (8M el)
    bf16_t* Vb     = (bf16_t*)(ws + 1024 + 20 * MiB);      // 16 MiB
    bf16_t* prev_c = (bf16_t*)(ws + 1024 + 36 * MiB);      //  4 MiB
    bf16_t* ctx_c  = (bf16_t*)(ws + 1024 + 40 * MiB);      // 16 MiB
    bf16_t* Wq_c   = (bf16_t*)(ws + 1024 + 56 * MiB);      //  2 MiB
    bf16_t* Wk_c   = (bf16_t*)(ws + 1024 + 58 * MiB);      //  2 MiB
    bf16_t* Wv_c   = (bf16_t*)(ws + 1024 + 60 * MiB);      //  2 MiB
    bf16_t* bq_c   = (bf16_t*)(ws + 1024 + 62 * MiB);
    bf16_t* bk_c   = bq_c + 1024;
    bf16_t* bv_c   = bk_c + 1024;

    dtype_probe<<<1, 256, 0, stream>>>((const unsigned short*)Wq, flag);

    const int NP = NBATCH * XLEN * D_MODEL;   // 2M
    const int NC = NBATCH * TLEN * D_MODEL;   // 8M
    const int NW = D_MODEL * D_MODEL;         // 1M
    convert_in<<<1024, 256, 0, stream>>>(prev, prev_c, NP, flag, 0);
    convert_in<<<1024, 256, 0, stream>>>(ctx,  ctx_c,  NC, flag, 0);
    convert_in<<<1024, 256, 0, stream>>>(Wq,   Wq_c,   NW, flag, 0);
    convert_in<<<1024, 256, 0, stream>>>(Wk,   Wk_c,   NW, flag, 0);
    convert_in<<<1024, 256, 0, stream>>>(Wv,   Wv_c,   NW, flag, 0);
    convert_in<<<4, 256, 0, stream>>>(bq, bq_c, D_MODEL, flag, 1);
    convert_in<<<4, 256, 0, stream>>>(bk, bk_c, D_MODEL, flag, 1);
    convert_in<<<4, 256, 0, stream>>>(bv, bv_c, D_MODEL, flag, 1);

    proj_gemm<<<(NBATCH * XLEN / 32) * 16 / 4, 256, 0, stream>>>(prev, prev_c, Wq, Wq_c, bq_c, Qb, NBATCH * XLEN, flag);
    proj_gemm<<<(NBATCH * TLEN / 32) * 16 / 4, 256, 0, stream>>>(ctx,  ctx_c,  Wk, Wk_c, bk_c, Kb, NBATCH * TLEN, flag);
    proj_gemm<<<(NBATCH * TLEN / 32) * 16 / 4, 256, 0, stream>>>(ctx,  ctx_c,  Wv, Wv_c, bv_c, Vb, NBATCH * TLEN, flag);
    attn_kernel<<<NBATCH * NHEAD * (XLEN / 64), 256, 0, stream>>>(Qb, Kb, Vb, d_out, flag);
}